// Round 2
// baseline (102.498 us; speedup 1.0000x reference)
//
#include <hip/hip_runtime.h>
#include <hip/hip_cooperative_groups.h>

namespace cg = cooperative_groups;

// Fast discrete Radon transform (exact, wrap-around shears), radix-16:
//   case A (m<512):   R_m[t]  = sum_y img[(t - m*y) & 511, y]
//   case B (m>=512):  R'_a[t] = sum_x img[x, (t - 2a*x) & 511], a = m-512
// out = R * (1/sqrt(512)), imag exactly 0.
//
// Stages: 1 ->(init, radix-2, case A only) 2 ->(radix-16) 32 ->(radix-16, fused output) 512.
// Case B: radix-2 fused into pass1's staging loads.
// All three stages run in ONE cooperative kernel (2 grid.sync), 768 blocks
// = 3 blocks/CU exactly (LDS 49.9 KB, launch_bounds caps VGPR for 6 waves/EU).

#define NN 512
#define MU 768
#define MASK 511
#define SCALE 0.04419417382415922f  // 1/sqrt(512)

// ---- phase 0: case A transpose + radix-2; img read exactly once ----------
__device__ __forceinline__ void init_body(int b, int bx, int t, float* S,
                                          const float* __restrict__ img,
                                          float* __restrict__ A0) {
  float (*T)[64][65] = (float (*)[64][65])S;
  const int xp = bx >> 2, wt = bx & 3;
  const int x0 = xp * 64, x1 = x0 + 256, w0 = wt * 64;
  const float* src = img + (size_t)b * NN * NN;
  float* dst = A0 + (size_t)b * (512 * NN);

  auto load_tile = [&](int tile, int xb, int wb, int idx) {
    const int r = (idx >> 4) & 63, c4 = (idx & 15) << 2;
    const float4 v = *(const float4*)&src[(size_t)(xb + r) * NN + wb + c4];
    T[tile][r][c4]     = v.x;
    T[tile][r][c4 + 1] = v.y;
    T[tile][r][c4 + 2] = v.z;
    T[tile][r][c4 + 3] = v.w;
  };
  auto store2 = [&](const float (*Ta)[65], const float (*Tb)[65], int rbase,
                    int cbase) {
    for (int idx = t; idx < 1024; idx += 512) {
      const int wl = idx >> 4, x4 = (idx & 15) << 2;
      float4 a;
      a.x = Ta[x4][wl]     + Tb[x4][wl];
      a.y = Ta[x4 + 1][wl] + Tb[x4 + 1][wl];
      a.z = Ta[x4 + 2][wl] + Tb[x4 + 2][wl];
      a.w = Ta[x4 + 3][wl] + Tb[x4 + 3][wl];
      *(float4*)&dst[(size_t)(rbase + wl) * NN + cbase + x4] = a;
    }
  };

  // phase 1: T0=(x0,w0) "T1a", T1=(x0,w0+256) "T2a", T2=(x1,w0+256) "T2b"
  for (int idx = t; idx < 3072; idx += 512) {
    const int tile = idx >> 10;
    load_tile(tile, (tile == 2) ? x1 : x0, (tile == 0) ? w0 : w0 + 256, idx);
  }
  __syncthreads();
  store2(T[0], T[1], w0, x0);        // class0 @ x0 = T1a + T2a
  store2(T[0], T[2], 256 + w0, x0);  // class1 @ x0 = T1a + T2b
  __syncthreads();
  // phase 2: T0 <- (x1, w0) "T1b" (overwrites T1a, no longer needed)
  for (int idx = t; idx < 1024; idx += 512) load_tile(0, x1, w0, idx);
  __syncthreads();
  store2(T[0], T[2], w0, x1);        // class0 @ x1 = T1b + T2b
  store2(T[0], T[1], 256 + w0, x1);  // class1 @ x1 = T1b + T2a
}

// ---- phase 1: stage 2 -> 32 (H=16, shifts %16==0 -> float4 LDS reads) ----
__device__ __forceinline__ void pass1_body(int b, int bx, int t, float* L,
                                           const float* __restrict__ A0,
                                           const float* __restrict__ img,
                                           float* __restrict__ A1,
                                           float* __restrict__ B1) {
  const bool isB = bx >= 32;
  const int c = isB ? 0 : (bx >> 4);
  const int w = isB ? (bx - 32) : (bx & 15);
  if (isB) {
    const float4* s4 = (const float4*)(img + (size_t)b * NN * NN);
    float4* l4 = (float4*)L;
    for (int it = 0; it < 4; ++it) {
      int flat = it * 512 + t;  // 2048 float4
      int lrow = flat >> 7, col = flat & 127;
      float4 u = s4[(w + 16 * lrow) * 128 + col];
      float4 v = s4[(w + 16 * lrow + 256) * 128 + col];
      u.x += v.x; u.y += v.y; u.z += v.z; u.w += v.w;
      l4[lrow * 128 + col] = u;
    }
  } else {
    const float4* s4 = (const float4*)(A0 + (size_t)b * 512 * NN);
    float4* l4 = (float4*)L;
    const int pbase = c * 256 + w;  // parent row bb: pbase + 16*bb
    for (int it = 0; it < 4; ++it) {
      int flat = it * 512 + t;  // 2048 float4
      int lrow = flat >> 7, col = flat & 127;
      l4[lrow * 128 + col] = s4[(pbase + 16 * lrow) * 128 + col];
    }
  }
  __syncthreads();
  const int g = t >> 7;            // 0..3
  const int x4 = (t & 127) * 4;
  float* outA = A1 + (size_t)b * 512 * NN;
  float* outB = B1 + (size_t)b * 256 * NN;
  for (int jj = 0; jj < 4; ++jj) {
    const int j = jj * 4 + g;
    const int C = isB ? (2 * j) : (c + 2 * j);
    float4 acc = {0.f, 0.f, 0.f, 0.f};
#pragma unroll
    for (int bb = 0; bb < 16; ++bb) {
      int base = (x4 - C * bb * 16) & MASK;  // %4==0: no wrap split
      float4 v = *(const float4*)&L[bb * 512 + base];
      acc.x += v.x; acc.y += v.y; acc.z += v.z; acc.w += v.w;
    }
    const int orow = isB ? (j * 16 + w) : (C * 16 + w);
    float* op = isB ? outB : outA;
    *(float4*)&op[(size_t)orow * NN + x4] = acc;
  }
}

// ---- phase 2: stage 32 -> 512 (H=1) + fused scale/float2 output ----------
__device__ __forceinline__ void pass2_body(int b, int bx, int t, float* L,
                                           const float* __restrict__ A1,
                                           const float* __restrict__ B1,
                                           float2* __restrict__ out) {
  const bool isB = bx >= 32;
  const int c = isB ? 2 * (bx - 32) : bx;
  const float* in = isB ? (B1 + (size_t)b * 256 * NN + (size_t)(c >> 1) * 16 * NN)
                        : (A1 + (size_t)b * 512 * NN + (size_t)c * 16 * NN);
  {
    const float4* s4 = (const float4*)in;
    float4* l4 = (float4*)L;
    for (int it = 0; it < 4; ++it) l4[it * 512 + t] = s4[it * 512 + t];
  }
  __syncthreads();
  float acc[16];
#pragma unroll
  for (int j = 0; j < 16; ++j) acc[j] = 0.f;
#pragma unroll
  for (int bb = 0; bb < 16; ++bb) {
    int base = (t - c * bb) & MASK;
    const int step = (32 * bb) & MASK;
    const float* row = L + bb * 512;
#pragma unroll
    for (int j = 0; j < 16; ++j) {
      acc[j] += row[base];          // consecutive lanes -> consecutive banks
      base = (base - step) & MASK;  // shift for C = c + 32*(j+1)
    }
  }
#pragma unroll
  for (int j = 0; j < 16; ++j) {
    int m = isB ? (512 + (c >> 1) + 16 * j) : (c + 32 * j);
    float2 o; o.x = acc[j] * SCALE; o.y = 0.f;
    out[((size_t)b * MU + m) * NN + t] = o;
  }
}

// ---- fused cooperative kernel: init -> sync -> pass1 -> sync -> pass2 ----
__global__ __launch_bounds__(512, 6) void drt_fused(const float* __restrict__ img,
                                                    float* __restrict__ A0,
                                                    float* __restrict__ A1,
                                                    float* __restrict__ B1,
                                                    float2* __restrict__ out) {
  __shared__ float S[3 * 64 * 65];  // 49.92 KB; phases 1/2 reuse as 16x512
  cg::grid_group grid = cg::this_grid();
  const int gb = blockIdx.x, t = threadIdx.x;
  if (gb < 256) init_body(gb >> 4, gb & 15, t, S, img, A0);
  grid.sync();
  pass1_body(gb / 48, gb % 48, t, S, A0, img, A1, B1);
  grid.sync();
  pass2_body(gb / 48, gb % 48, t, S, A1, B1, out);
}

// ---- standalone 3-kernel path (fallback if cooperative launch refused) ---
__global__ __launch_bounds__(512) void k_init(const float* __restrict__ img,
                                              float* __restrict__ A0) {
  __shared__ float S[3 * 64 * 65];
  init_body(blockIdx.y, blockIdx.x, threadIdx.x, S, img, A0);
}
__global__ __launch_bounds__(512) void k_pass1(const float* __restrict__ A0,
                                               const float* __restrict__ img,
                                               float* __restrict__ A1,
                                               float* __restrict__ B1) {
  __shared__ float L[16 * 512];
  pass1_body(blockIdx.y, blockIdx.x, threadIdx.x, L, A0, img, A1, B1);
}
__global__ __launch_bounds__(512) void k_pass2(const float* __restrict__ A1,
                                               const float* __restrict__ B1,
                                               float2* __restrict__ out) {
  __shared__ float L[16 * 512];
  pass2_body(blockIdx.y, blockIdx.x, threadIdx.x, L, A1, B1, out);
}

// ================= fallback: round-1 direct shear-sum =====================
#define TM 16
#define YT 16
#define LDS_STRIDE 516
__global__ __launch_bounds__(512) void drt_main(const float* __restrict__ img,
                                                float* __restrict__ out) {
  __shared__ float rows[YT * LDS_STRIDE];
  const int b = blockIdx.y;
  const int tile = blockIdx.x;
  const int t = threadIdx.x;
  const bool caseB = (tile >= 32);
  const int a0 = caseB ? (tile - 32) * TM : tile * TM;
  const float* __restrict__ src = img + (size_t)b * (NN * NN);
  const int slope0 = caseB ? (2 * a0) : a0;
  const int dslope = caseB ? 2 : 1;
  float acc[TM];
#pragma unroll
  for (int i = 0; i < TM; ++i) acc[i] = 0.0f;
  for (int y0 = 0; y0 < NN; y0 += YT) {
    __syncthreads();
    if (caseB) {
#pragma unroll
      for (int r = 0; r < YT; ++r) rows[r * LDS_STRIDE + t] = src[(y0 + r) * NN + t];
    } else {
#pragma unroll
      for (int rep = 0; rep < YT; ++rep) {
        int idx = rep * NN + t;
        int xx = idx >> 4, cc = idx & 15;
        rows[cc * LDS_STRIDE + xx] = src[xx * NN + y0 + cc];
      }
    }
    __syncthreads();
#pragma unroll 4
    for (int r = 0; r < YT; ++r) {
      const int v = y0 + r;
      int base = t - slope0 * v;
      const int step = dslope * v;
      const float* __restrict__ rowp = rows + r * LDS_STRIDE;
#pragma unroll
      for (int i = 0; i < TM; ++i) { acc[i] += rowp[base & MASK]; base -= step; }
    }
  }
  const int m = caseB ? (NN + a0) : a0;
  float2* outp = (float2*)out;
#pragma unroll
  for (int i = 0; i < TM; ++i) {
    float2 vv; vv.x = acc[i] * SCALE; vv.y = 0.0f;
    outp[((size_t)b * MU + (m + i)) * NN + t] = vv;
  }
}

extern "C" void kernel_launch(void* const* d_in, const int* in_sizes, int n_in,
                              void* d_out, int out_size, void* d_ws, size_t ws_size,
                              hipStream_t stream) {
  const float* img = (const float*)d_in[0];
  if (ws_size < (size_t)42 * 1024 * 1024) {
    drt_main<<<dim3(48, 16), dim3(512), 0, stream>>>(img, (float*)d_out);
    return;
  }
  float* W  = (float*)d_ws;
  float* A0 = W;                 // 16 x 512 x 512
  float* A1 = W + 4194304;       // 16 x 512 x 512
  float* B1 = W + 8388608;       // 16 x 256 x 512
  float2* outp = (float2*)d_out;

  static int coopOk = -1;
  if (coopOk < 0) {
    int nb = 0;
    hipError_t qe = hipOccupancyMaxActiveBlocksPerMultiprocessor(
        &nb, (const void*)drt_fused, 512, 0);
    coopOk = (qe == hipSuccess && nb >= 3) ? 1 : 0;
  }
  if (coopOk == 1) {
    void* args[] = {(void*)&img, (void*)&A0, (void*)&A1, (void*)&B1,
                    (void*)&outp};
    hipError_t e = hipLaunchCooperativeKernel((const void*)drt_fused,
                                              dim3(768), dim3(512), args, 0,
                                              stream);
    if (e == hipSuccess) return;
    coopOk = 0;  // don't retry a refused path
  }
  k_init <<<dim3(16, 16), dim3(512), 0, stream>>>(img, A0);
  k_pass1<<<dim3(48, 16), dim3(512), 0, stream>>>(A0, img, A1, B1);
  k_pass2<<<dim3(48, 16), dim3(512), 0, stream>>>(A1, B1, outp);
}

// Round 4
// 101.278 us; speedup vs baseline: 1.0120x; 1.0120x over previous
//
#include <hip/hip_runtime.h>

// Fast discrete Radon transform (exact, wrap-around shears), radix-16:
//   case A (m<512):   R_m[t]  = sum_y img[(t - m*y) & 511, y]
//   case B (m>=512):  R'_a[t] = sum_x img[x, (t - 2a*x) & 511], a = m-512
// out = R * (1/sqrt(512)), imag exactly 0.
//
// Stages: 1 ->(init, radix-2, case A only) 2 ->(radix-16) 32 ->(radix-16, fused output) 512.
// Case B: radix-2 fused into pass1's staging loads (no B0 buffer).
// LDS-gather redundancy elimination: at inner-row bb the j-shift is
// 32*bb*j mod 512 -> only 16/gcd(bb,16) distinct elements; read once,
// add into all j sharing the shift. Bit-exact (same value, same bb order).

#define NN 512
#define MU 768
#define MASK 511
#define SCALE 0.04419417382415922f  // 1/sqrt(512)

// ---- init: case A transpose + radix-2; img read exactly once -------------
__global__ __launch_bounds__(512) void k_init(const float* __restrict__ img,
                                              float* __restrict__ A0) {
  __shared__ float T[3][64][65];
  const int bx = blockIdx.x, b = blockIdx.y;
  const int xp = bx >> 2, wt = bx & 3;
  const int x0 = xp * 64, x1 = x0 + 256, w0 = wt * 64;
  const float* src = img + (size_t)b * NN * NN;
  float* dst = A0 + (size_t)b * (512 * NN);

  auto load_tile = [&](int tile, int xb, int wb, int idx) {
    const int r = (idx >> 4) & 63, c4 = (idx & 15) << 2;
    const float4 v = *(const float4*)&src[(size_t)(xb + r) * NN + wb + c4];
    T[tile][r][c4]     = v.x;
    T[tile][r][c4 + 1] = v.y;
    T[tile][r][c4 + 2] = v.z;
    T[tile][r][c4 + 3] = v.w;
  };
  auto store2 = [&](const float (*Ta)[65], const float (*Tb)[65], int rbase,
                    int cbase) {
    for (int idx = threadIdx.x; idx < 1024; idx += 512) {
      const int wl = idx >> 4, x4 = (idx & 15) << 2;
      float4 a;
      a.x = Ta[x4][wl]     + Tb[x4][wl];
      a.y = Ta[x4 + 1][wl] + Tb[x4 + 1][wl];
      a.z = Ta[x4 + 2][wl] + Tb[x4 + 2][wl];
      a.w = Ta[x4 + 3][wl] + Tb[x4 + 3][wl];
      *(float4*)&dst[(size_t)(rbase + wl) * NN + cbase + x4] = a;
    }
  };

  for (int idx = threadIdx.x; idx < 3072; idx += 512) {
    const int tile = idx >> 10;
    load_tile(tile, (tile == 2) ? x1 : x0, (tile == 0) ? w0 : w0 + 256, idx);
  }
  __syncthreads();
  store2(T[0], T[1], w0, x0);        // class0 @ x0 = T1a + T2a
  store2(T[0], T[2], 256 + w0, x0);  // class1 @ x0 = T1a + T2b
  __syncthreads();
  for (int idx = threadIdx.x; idx < 1024; idx += 512) load_tile(0, x1, w0, idx);
  __syncthreads();
  store2(T[0], T[2], w0, x1);        // class0 @ x1 = T1b + T2b
  store2(T[0], T[1], 256 + w0, x1);  // class1 @ x1 = T1b + T2a
}

// ---- pass 1: stage 2 -> 32 (H=16, shifts %16==0 -> float4 LDS reads) -----
// Per thread: j = 4*jj + g, C = C0 + 8*jj, shift(jj) = 128*bb*jj mod 512
// -> distinct reads per bb: bb%4==0 -> 1, bb%4==2 -> 2, odd -> 4 (44 vs 64).
__global__ __launch_bounds__(512) void k_pass1(const float* __restrict__ A0,
                                               const float* __restrict__ img,
                                               float* __restrict__ A1,
                                               float* __restrict__ B1) {
  __shared__ float L[16 * 512];
  const int bx = blockIdx.x, b = blockIdx.y;
  const int t = threadIdx.x;
  const bool isB = bx >= 32;
  const int c = isB ? 0 : (bx >> 4);
  const int w = isB ? (bx - 32) : (bx & 15);
  if (isB) {
    const float4* s4 = (const float4*)(img + (size_t)b * NN * NN);
    float4* l4 = (float4*)L;
    for (int it = 0; it < 4; ++it) {
      int flat = it * 512 + t;  // 2048 float4
      int lrow = flat >> 7, col = flat & 127;
      float4 u = s4[(w + 16 * lrow) * 128 + col];
      float4 v = s4[(w + 16 * lrow + 256) * 128 + col];
      u.x += v.x; u.y += v.y; u.z += v.z; u.w += v.w;
      l4[lrow * 128 + col] = u;
    }
  } else {
    const float4* s4 = (const float4*)(A0 + (size_t)b * 512 * NN);
    float4* l4 = (float4*)L;
    const int pbase = c * 256 + w;  // parent row bb: pbase + 16*bb
    for (int it = 0; it < 4; ++it) {
      int flat = it * 512 + t;  // 2048 float4
      int lrow = flat >> 7, col = flat & 127;
      l4[lrow * 128 + col] = s4[(pbase + 16 * lrow) * 128 + col];
    }
  }
  __syncthreads();
  const int g = t >> 7;            // 0..3
  const int x4 = (t & 127) * 4;
  const int C0 = isB ? (2 * g) : (c + 2 * g);
  float* outA = A1 + (size_t)b * 512 * NN;
  float* outB = B1 + (size_t)b * 256 * NN;
  float4 acc[4];
#pragma unroll
  for (int jj = 0; jj < 4; ++jj) acc[jj] = make_float4(0.f, 0.f, 0.f, 0.f);
#pragma unroll
  for (int bb = 0; bb < 16; ++bb) {
    const int p = ((bb & 3) == 0) ? 1 : (((bb & 1) == 0) ? 2 : 4);
    const int step = (128 * bb) & MASK;
    int base = (x4 - C0 * bb * 16) & MASK;  // %4==0: no wrap split
    float4 v[4];
#pragma unroll
    for (int k = 0; k < 4; ++k)
      if (k < p) {
        v[k] = *(const float4*)&L[bb * 512 + base];
        base = (base - step) & MASK;
      }
#pragma unroll
    for (int jj = 0; jj < 4; ++jj) {
      const float4 u = v[jj & (p - 1)];
      acc[jj].x += u.x; acc[jj].y += u.y; acc[jj].z += u.z; acc[jj].w += u.w;
    }
  }
#pragma unroll
  for (int jj = 0; jj < 4; ++jj) {
    const int j = 4 * jj + g;
    const int C = C0 + 8 * jj;
    const int orow = isB ? (j * 16 + w) : (C * 16 + w);
    float* op = isB ? outB : outA;
    *(float4*)&op[(size_t)orow * NN + x4] = acc[jj];
  }
}

// ---- pass 2: stage 32 -> 512 (H=1) + fused scale/float2 output -----------
// shift(j) = 32*bb*j mod 512 -> distinct reads per bb: 16/gcd(bb,16)
// (bb=0:1, bb=8:2, bb%4==0:4, bb%2==0:8, odd:16) => 171 vs 256 reads.
__global__ __launch_bounds__(512) void k_pass2(const float* __restrict__ A1,
                                               const float* __restrict__ B1,
                                               float2* __restrict__ out) {
  __shared__ float L[16 * 512];
  const int bx = blockIdx.x, b = blockIdx.y;
  const int t = threadIdx.x;  // = x
  const bool isB = bx >= 32;
  const int c = isB ? 2 * (bx - 32) : bx;
  const float* in = isB ? (B1 + (size_t)b * 256 * NN + (size_t)(c >> 1) * 16 * NN)
                        : (A1 + (size_t)b * 512 * NN + (size_t)c * 16 * NN);
  {
    const float4* s4 = (const float4*)in;
    float4* l4 = (float4*)L;
    for (int it = 0; it < 4; ++it) l4[it * 512 + t] = s4[it * 512 + t];
  }
  __syncthreads();
  float acc[16];
#pragma unroll
  for (int j = 0; j < 16; ++j) acc[j] = 0.f;
#pragma unroll
  for (int bb = 0; bb < 16; ++bb) {
    const int p = (bb == 0) ? 1
                : ((bb & 1) ? 16 : ((bb & 2) ? 8 : ((bb & 4) ? 4 : 2)));
    const int step = (32 * bb) & MASK;
    const float* row = L + bb * 512;
    int base = (t - c * bb) & MASK;
    float v[16];
#pragma unroll
    for (int k = 0; k < 16; ++k)
      if (k < p) {
        v[k] = row[base];            // consecutive lanes -> consecutive banks
        base = (base - step) & MASK;
      }
#pragma unroll
    for (int j = 0; j < 16; ++j) acc[j] += v[j & (p - 1)];
  }
#pragma unroll
  for (int j = 0; j < 16; ++j) {
    int m = isB ? (512 + (c >> 1) + 16 * j) : (c + 32 * j);
    float2 o; o.x = acc[j] * SCALE; o.y = 0.f;
    out[((size_t)b * MU + m) * NN + t] = o;
  }
}

// ================= fallback: round-1 direct shear-sum =====================
#define TM 16
#define YT 16
#define LDS_STRIDE 516
__global__ __launch_bounds__(512) void drt_main(const float* __restrict__ img,
                                                float* __restrict__ out) {
  __shared__ float rows[YT * LDS_STRIDE];
  const int b = blockIdx.y;
  const int tile = blockIdx.x;
  const int t = threadIdx.x;
  const bool caseB = (tile >= 32);
  const int a0 = caseB ? (tile - 32) * TM : tile * TM;
  const float* __restrict__ src = img + (size_t)b * (NN * NN);
  const int slope0 = caseB ? (2 * a0) : a0;
  const int dslope = caseB ? 2 : 1;
  float acc[TM];
#pragma unroll
  for (int i = 0; i < TM; ++i) acc[i] = 0.0f;
  for (int y0 = 0; y0 < NN; y0 += YT) {
    __syncthreads();
    if (caseB) {
#pragma unroll
      for (int r = 0; r < YT; ++r) rows[r * LDS_STRIDE + t] = src[(y0 + r) * NN + t];
    } else {
#pragma unroll
      for (int rep = 0; rep < YT; ++rep) {
        int idx = rep * NN + t;
        int xx = idx >> 4, cc = idx & 15;
        rows[cc * LDS_STRIDE + xx] = src[xx * NN + y0 + cc];
      }
    }
    __syncthreads();
#pragma unroll 4
    for (int r = 0; r < YT; ++r) {
      const int v = y0 + r;
      int base = t - slope0 * v;
      const int step = dslope * v;
      const float* __restrict__ rowp = rows + r * LDS_STRIDE;
#pragma unroll
      for (int i = 0; i < TM; ++i) { acc[i] += rowp[base & MASK]; base -= step; }
    }
  }
  const int m = caseB ? (NN + a0) : a0;
  float2* outp = (float2*)out;
#pragma unroll
  for (int i = 0; i < TM; ++i) {
    float2 vv; vv.x = acc[i] * SCALE; vv.y = 0.0f;
    outp[((size_t)b * MU + (m + i)) * NN + t] = vv;
  }
}

extern "C" void kernel_launch(void* const* d_in, const int* in_sizes, int n_in,
                              void* d_out, int out_size, void* d_ws, size_t ws_size,
                              hipStream_t stream) {
  const float* img = (const float*)d_in[0];
  if (ws_size < (size_t)42 * 1024 * 1024) {
    drt_main<<<dim3(48, 16), dim3(512), 0, stream>>>(img, (float*)d_out);
    return;
  }
  float* W  = (float*)d_ws;
  float* A0 = W;                 // 16 x 512 x 512
  float* A1 = W + 4194304;       // 16 x 512 x 512
  float* B1 = W + 8388608;       // 16 x 256 x 512

  k_init <<<dim3(16, 16), dim3(512), 0, stream>>>(img, A0);
  k_pass1<<<dim3(48, 16), dim3(512), 0, stream>>>(A0, img, A1, B1);
  k_pass2<<<dim3(48, 16), dim3(512), 0, stream>>>(A1, B1, (float2*)d_out);
}

// Round 6
// 98.046 us; speedup vs baseline: 1.0454x; 1.0330x over previous
//
#include <hip/hip_runtime.h>

// Fast discrete Radon transform (exact, wrap-around shears), radix-16:
//   case A (m<512):   R_m[t]  = sum_y img[(t - m*y) & 511, y]
//   case B (m>=512):  R'_a[t] = sum_x img[x, (t - 2a*x) & 511], a = m-512
// out = R * (1/sqrt(512)), imag exactly 0.
//
// Stages: 1 ->(init, radix-2, case A only) 2 ->(radix-16) 32 ->(radix-16, fused output) 512.
// Case B: radix-2 fused into pass1's staging loads (no B0 buffer).
// k_init: all 4 transpose tiles resident (33KB LDS), ONE barrier, 2 blocks/CU.
// LDS-gather redundancy elimination in pass1/pass2 (bit-exact).

#define NN 512
#define MU 768
#define MASK 511
#define SCALE 0.04419417382415922f  // 1/sqrt(512)

// ---- init: case A transpose + radix-2; img read exactly once -------------
// Block = (x-tile pair {x0,x0+256}) x (32-wide w tile). Tiles:
//   T0=(x0,w0) T1=(x0,w0+256) T2=(x1,w0) T3=(x1,w0+256)
// Outputs: cls0@x0=T0+T1, cls1@x0=T0+T3, cls0@x1=T2+T3, cls1@x1=T2+T1.
__global__ __launch_bounds__(512) void k_init(const float* __restrict__ img,
                                              float* __restrict__ A0) {
  __shared__ float T[4][64][33];
  const int bx = blockIdx.x, b = blockIdx.y;
  const int xp = bx >> 3, wt = bx & 7;       // xp<4, wt<8
  const int x0 = xp * 64, x1 = x0 + 256, w0 = wt * 32;
  const float* src = img + (size_t)b * NN * NN;
  float* dst = A0 + (size_t)b * (512 * NN);

  for (int idx = threadIdx.x; idx < 2048; idx += 512) {
    const int tile = idx >> 9;               // 0..3
    const int r = (idx >> 3) & 63, c4 = (idx & 7) << 2;
    const int xb = (tile & 2) ? x1 : x0;
    const int wb = (tile & 1) ? (w0 + 256) : w0;
    const float4 v = *(const float4*)&src[(size_t)(xb + r) * NN + wb + c4];
    T[tile][r][c4]     = v.x;
    T[tile][r][c4 + 1] = v.y;
    T[tile][r][c4 + 2] = v.z;
    T[tile][r][c4 + 3] = v.w;
  }
  __syncthreads();
  for (int idx = threadIdx.x; idx < 2048; idx += 512) {
    const int s = idx >> 9;                  // 0..3 output set
    const int wl = (idx >> 4) & 31, x4 = (idx & 15) << 2;
    const int ta = (s & 2) ? 2 : 0;
    const int tb = (s == 0) ? 1 : (s == 1) ? 3 : (s == 2) ? 3 : 1;
    const int rbase = ((s & 1) ? 256 : 0) + w0;
    const int cbase = (s & 2) ? x1 : x0;
    float4 a;
    a.x = T[ta][x4][wl]     + T[tb][x4][wl];
    a.y = T[ta][x4 + 1][wl] + T[tb][x4 + 1][wl];
    a.z = T[ta][x4 + 2][wl] + T[tb][x4 + 2][wl];
    a.w = T[ta][x4 + 3][wl] + T[tb][x4 + 3][wl];
    *(float4*)&dst[(size_t)(rbase + wl) * NN + cbase + x4] = a;
  }
}

// ---- pass 1: stage 2 -> 32 (H=16, shifts %16==0 -> float4 LDS reads) -----
// Per thread: j = 4*jj + g, C = C0 + 8*jj, shift(jj) = 128*bb*jj mod 512
// -> distinct reads per bb: bb%4==0 -> 1, bb%4==2 -> 2, odd -> 4 (44 vs 64).
__global__ __launch_bounds__(512) void k_pass1(const float* __restrict__ A0,
                                               const float* __restrict__ img,
                                               float* __restrict__ A1,
                                               float* __restrict__ B1) {
  __shared__ float L[16 * 512];
  const int bx = blockIdx.x, b = blockIdx.y;
  const int t = threadIdx.x;
  const bool isB = bx >= 32;
  const int c = isB ? 0 : (bx >> 4);
  const int w = isB ? (bx - 32) : (bx & 15);
  if (isB) {
    const float4* s4 = (const float4*)(img + (size_t)b * NN * NN);
    float4* l4 = (float4*)L;
    for (int it = 0; it < 4; ++it) {
      int flat = it * 512 + t;  // 2048 float4
      int lrow = flat >> 7, col = flat & 127;
      float4 u = s4[(w + 16 * lrow) * 128 + col];
      float4 v = s4[(w + 16 * lrow + 256) * 128 + col];
      u.x += v.x; u.y += v.y; u.z += v.z; u.w += v.w;
      l4[lrow * 128 + col] = u;
    }
  } else {
    const float4* s4 = (const float4*)(A0 + (size_t)b * 512 * NN);
    float4* l4 = (float4*)L;
    const int pbase = c * 256 + w;  // parent row bb: pbase + 16*bb
    for (int it = 0; it < 4; ++it) {
      int flat = it * 512 + t;  // 2048 float4
      int lrow = flat >> 7, col = flat & 127;
      l4[lrow * 128 + col] = s4[(pbase + 16 * lrow) * 128 + col];
    }
  }
  __syncthreads();
  const int g = t >> 7;            // 0..3
  const int x4 = (t & 127) * 4;
  const int C0 = isB ? (2 * g) : (c + 2 * g);
  float* outA = A1 + (size_t)b * 512 * NN;
  float* outB = B1 + (size_t)b * 256 * NN;
  float4 acc[4];
#pragma unroll
  for (int jj = 0; jj < 4; ++jj) acc[jj] = make_float4(0.f, 0.f, 0.f, 0.f);
#pragma unroll
  for (int bb = 0; bb < 16; ++bb) {
    const int p = ((bb & 3) == 0) ? 1 : (((bb & 1) == 0) ? 2 : 4);
    const int step = (128 * bb) & MASK;
    int base = (x4 - C0 * bb * 16) & MASK;  // %4==0: no wrap split
    float4 v[4];
#pragma unroll
    for (int k = 0; k < 4; ++k)
      if (k < p) {
        v[k] = *(const float4*)&L[bb * 512 + base];
        base = (base - step) & MASK;
      }
#pragma unroll
    for (int jj = 0; jj < 4; ++jj) {
      const float4 u = v[jj & (p - 1)];
      acc[jj].x += u.x; acc[jj].y += u.y; acc[jj].z += u.z; acc[jj].w += u.w;
    }
  }
#pragma unroll
  for (int jj = 0; jj < 4; ++jj) {
    const int j = 4 * jj + g;
    const int C = C0 + 8 * jj;
    const int orow = isB ? (j * 16 + w) : (C * 16 + w);
    float* op = isB ? outB : outA;
    *(float4*)&op[(size_t)orow * NN + x4] = acc[jj];
  }
}

// ---- pass 2: stage 32 -> 512 (H=1) + fused scale/float2 output -----------
// shift(j) = 32*bb*j mod 512 -> distinct reads per bb: 16/gcd(bb,16)
// (bb=0:1, bb=8:2, bb%4==0:4, bb%2==0:8, odd:16) => 171 vs 256 reads.
__global__ __launch_bounds__(512) void k_pass2(const float* __restrict__ A1,
                                               const float* __restrict__ B1,
                                               float2* __restrict__ out) {
  __shared__ float L[16 * 512];
  const int bx = blockIdx.x, b = blockIdx.y;
  const int t = threadIdx.x;  // = x
  const bool isB = bx >= 32;
  const int c = isB ? 2 * (bx - 32) : bx;
  const float* in = isB ? (B1 + (size_t)b * 256 * NN + (size_t)(c >> 1) * 16 * NN)
                        : (A1 + (size_t)b * 512 * NN + (size_t)c * 16 * NN);
  {
    const float4* s4 = (const float4*)in;
    float4* l4 = (float4*)L;
    for (int it = 0; it < 4; ++it) l4[it * 512 + t] = s4[it * 512 + t];
  }
  __syncthreads();
  float acc[16];
#pragma unroll
  for (int j = 0; j < 16; ++j) acc[j] = 0.f;
#pragma unroll
  for (int bb = 0; bb < 16; ++bb) {
    const int p = (bb == 0) ? 1
                : ((bb & 1) ? 16 : ((bb & 2) ? 8 : ((bb & 4) ? 4 : 2)));
    const int step = (32 * bb) & MASK;
    const float* row = L + bb * 512;
    int base = (t - c * bb) & MASK;
    float v[16];
#pragma unroll
    for (int k = 0; k < 16; ++k)
      if (k < p) {
        v[k] = row[base];            // consecutive lanes -> consecutive banks
        base = (base - step) & MASK;
      }
#pragma unroll
    for (int j = 0; j < 16; ++j) acc[j] += v[j & (p - 1)];
  }
#pragma unroll
  for (int j = 0; j < 16; ++j) {
    int m = isB ? (512 + (c >> 1) + 16 * j) : (c + 32 * j);
    float2 o; o.x = acc[j] * SCALE; o.y = 0.f;
    out[((size_t)b * MU + m) * NN + t] = o;
  }
}

// ================= fallback: round-1 direct shear-sum =====================
#define TM 16
#define YT 16
#define LDS_STRIDE 516
__global__ __launch_bounds__(512) void drt_main(const float* __restrict__ img,
                                                float* __restrict__ out) {
  __shared__ float rows[YT * LDS_STRIDE];
  const int b = blockIdx.y;
  const int tile = blockIdx.x;
  const int t = threadIdx.x;
  const bool caseB = (tile >= 32);
  const int a0 = caseB ? (tile - 32) * TM : tile * TM;
  const float* __restrict__ src = img + (size_t)b * (NN * NN);
  const int slope0 = caseB ? (2 * a0) : a0;
  const int dslope = caseB ? 2 : 1;
  float acc[TM];
#pragma unroll
  for (int i = 0; i < TM; ++i) acc[i] = 0.0f;
  for (int y0 = 0; y0 < NN; y0 += YT) {
    __syncthreads();
    if (caseB) {
#pragma unroll
      for (int r = 0; r < YT; ++r) rows[r * LDS_STRIDE + t] = src[(y0 + r) * NN + t];
    } else {
#pragma unroll
      for (int rep = 0; rep < YT; ++rep) {
        int idx = rep * NN + t;
        int xx = idx >> 4, cc = idx & 15;
        rows[cc * LDS_STRIDE + xx] = src[xx * NN + y0 + cc];
      }
    }
    __syncthreads();
#pragma unroll 4
    for (int r = 0; r < YT; ++r) {
      const int v = y0 + r;
      int base = t - slope0 * v;
      const int step = dslope * v;
      const float* __restrict__ rowp = rows + r * LDS_STRIDE;
#pragma unroll
      for (int i = 0; i < TM; ++i) { acc[i] += rowp[base & MASK]; base -= step; }
    }
  }
  const int m = caseB ? (NN + a0) : a0;
  float2* outp = (float2*)out;
#pragma unroll
  for (int i = 0; i < TM; ++i) {
    float2 vv; vv.x = acc[i] * SCALE; vv.y = 0.0f;
    outp[((size_t)b * MU + (m + i)) * NN + t] = vv;
  }
}

extern "C" void kernel_launch(void* const* d_in, const int* in_sizes, int n_in,
                              void* d_out, int out_size, void* d_ws, size_t ws_size,
                              hipStream_t stream) {
  const float* img = (const float*)d_in[0];
  if (ws_size < (size_t)42 * 1024 * 1024) {
    drt_main<<<dim3(48, 16), dim3(512), 0, stream>>>(img, (float*)d_out);
    return;
  }
  float* W  = (float*)d_ws;
  float* A0 = W;                 // 16 x 512 x 512
  float* A1 = W + 4194304;       // 16 x 512 x 512
  float* B1 = W + 8388608;       // 16 x 256 x 512

  k_init <<<dim3(32, 16), dim3(512), 0, stream>>>(img, A0);
  k_pass1<<<dim3(48, 16), dim3(512), 0, stream>>>(A0, img, A1, B1);
  k_pass2<<<dim3(48, 16), dim3(512), 0, stream>>>(A1, B1, (float2*)d_out);
}